// Round 17
// baseline (1548.791 us; speedup 1.0000x reference)
//
#include <hip/hip_runtime.h>

#define NL 50000
#define NS 128
#define G 160
#define GSQ (160*160)
#define GCUBE (160*160*160)
#define NRB 196             // ray blocks of 256 (196*256 = 50176 >= NL)
#define NBINS (G*2)         // (plane, row-half) bins = 320
#define ENT_CAP 11500000

struct RayParam { float4 a, b; };  // a={A,B,AR,BR}  b={AC,BC,cb,pad}

__device__ __forceinline__ void lds_add(float* p, float v) {
    atomicAdd(p, v);   // non-returning ds_add_f32
}

__device__ __forceinline__ float frcp(float x) {
#if __has_builtin(__builtin_amdgcn_rcpf)
    return __builtin_amdgcn_rcpf(x);
#else
    return 1.0f / x;
#endif
}

// f -> (base index, frac weight); identical math to reference.
__device__ __forceinline__ void coordf(float pos, int& i, float& w) {
    float f = (pos + 100.0f) * 0.8f - 0.5f;
    f = fminf(fmaxf(f, 0.0f), 159.0f);
    int ii = (int)f; ii = ii > 158 ? 158 : ii;
    i = ii; w = f - (float)ii;
}

// Padded sample window for (slab line f=A+B*t, plane p). Same in count/write;
// bp's fa>=0 recheck filters the padding.
__device__ __forceinline__ int cnt_for(float A, float B, float rB, int p, int& slo_out) {
    const float glo = (p <= 1)   ? -1.0f  : (float)(p - 1);
    const float ghi = (p >= 158) ? 160.0f : (float)(p + 1);
    int slo, shi;
    if (B == 0.0f) {
        if (A < glo || A > ghi) { slo_out = 0; return 0; }
        slo = 0; shi = NS - 1;
    } else {
        const float t1 = (glo - A) * rB, t2 = (ghi - A) * rB;
        const float tlo = fminf(t1, t2), thi = fmaxf(t1, t2);
        float slof = ceilf (tlo * (float)NS - 0.75f);
        float shif = floorf(thi * (float)NS - 0.25f);
        slof = fminf(fmaxf(slof,  0.0f), 127.0f);
        shif = fminf(fmaxf(shif, -1.0f), 127.0f);
        slo = (int)slof; shi = (int)shif;
    }
    slo_out = slo;
    return shi - slo + 1;   // may be <= 0
}

// Split the (ray,plane) window into row-half sub-windows (conservative +-1
// sample overlap at the fR=80 crossing; bp rechecks ib-half exactly). [r11]
__device__ __forceinline__ void halves_for(
    float A, float B, float rB, int p, float AR, float BR,
    int& lo0, int& n0, int& lo1, int& n1)
{
    lo0 = lo1 = 0; n0 = n1 = 0;
    int slo; const int c = cnt_for(A, B, rB, p, slo);
    if (c <= 0) return;
    const int shi = slo + c - 1;
    if (BR == 0.0f) {
        if (AR < 80.0f) { lo0 = slo; n0 = c; } else { lo1 = slo; n1 = c; }
        return;
    }
    float sstar = ((80.0f - AR) * frcp(BR)) * (float)NS - 0.5f;
    sstar = fminf(fmaxf(sstar, -300.0f), 300.0f);
    float lo0f, hi0f, lo1f, hi1f;
    if (BR > 0.0f) {   // fR rising: low-s side is half0
        lo0f = (float)slo;  hi0f = fminf((float)shi, floorf(sstar) + 1.0f);
        lo1f = fmaxf((float)slo, ceilf(sstar) - 1.0f);  hi1f = (float)shi;
    } else {
        lo1f = (float)slo;  hi1f = fminf((float)shi, floorf(sstar) + 1.0f);
        lo0f = fmaxf((float)slo, ceilf(sstar) - 1.0f);  hi0f = (float)shi;
    }
    lo0 = (int)lo0f; n0 = (int)hi0f - lo0 + 1; if (n0 < 0) n0 = 0;
    lo1 = (int)lo1f; n1 = (int)hi1f - lo1 + 1; if (n1 < 0) n1 = 0;
}

__device__ __forceinline__ void plane_range(float A, float B, int& plo, int& phi) {
    const float f0 = A + B * (0.5f / NS);
    const float f1 = A + B * (((float)NS - 0.5f) / NS);
    const float fmn = fminf(f0, f1), fmx = fmaxf(f0, f1);
    plo = (int)fmaxf(ceilf (fmn - 1.01f), 0.0f);
    phi = (int)fminf(floorf(fmx + 1.01f), 159.0f);
}

// ---------------- Stage 1: projection + param packing + FUSED bin count ----------------
// float2 pair-loads; ray params are wave-uniform, so after the reduction all
// 64 lanes count covered planes in parallel into the WG-shared histogram.
// The SAME registers lane 0 stores to params[] drive the count (bit-identical
// to what bin_write will reload).
template<int PA, int PB, int PC, int QS, int QR, int QC>
__device__ __forceinline__ void proj_body(
    const float* __restrict__ img,
    const float* __restrict__ lors,
    float* __restrict__ contrib,
    RayParam* __restrict__ params,
    int* __restrict__ cnt,              // LDS histogram (or nullptr)
    int sa, int sb, int bx)
{
    const int wave = threadIdx.x >> 6;
    const int lane = threadIdx.x & 63;
    const int lor  = bx * 4 + wave;

    const float p1x = lors[0*NL + lor];
    const float p1y = lors[1*NL + lor];
    const float p1z = lors[2*NL + lor];
    const float dxv = lors[3*NL + lor] - p1x;
    const float dyv = lors[4*NL + lor] - p1y;
    const float dzv = lors[5*NL + lor] - p1z;
    const float len  = sqrtf(dxv*dxv + dyv*dyv + dzv*dzv);
    const float step = len * (1.0f/NS);

    float2 P00[2], P01[2], P10[2], P11[2];
    float waq[2], wbq[2], wcq[2];

    #pragma unroll
    for (int q = 0; q < 2; ++q) {
        const int s = lane + q*64;
        const float t = ((float)s + 0.5f) * (1.0f/NS);
        const float pos[3] = { p1x + t*dxv, p1y + t*dyv, p1z + t*dzv };
        int ia, ib, ic; float wa, wb, wc;
        coordf(pos[PA], ia, wa);
        coordf(pos[PB], ib, wb);
        coordf(pos[PC], ic, wc);
        const float* g = img + ia*sa + ib*sb + ic;
        __builtin_memcpy(&P00[q], g,            8);
        __builtin_memcpy(&P01[q], g + sb,       8);
        __builtin_memcpy(&P10[q], g + sa,       8);
        __builtin_memcpy(&P11[q], g + sa + sb,  8);
        waq[q] = wa; wbq[q] = wb; wcq[q] = wc;
    }

    float sum = 0.0f;
    #pragma unroll
    for (int q = 0; q < 2; ++q) {
        const float wa = waq[q], wb = wbq[q], wc = wcq[q];
        const float c00 = P00[q].x + wc*(P00[q].y - P00[q].x);
        const float c01 = P01[q].x + wc*(P01[q].y - P01[q].x);
        const float c10 = P10[q].x + wc*(P10[q].y - P10[q].x);
        const float c11 = P11[q].x + wc*(P11[q].y - P11[q].x);
        const float c0  = c00 + wb*(c01 - c00);
        const float c1  = c10 + wb*(c11 - c10);
        sum += c0 + wa*(c1 - c0);
    }

    #pragma unroll
    for (int off = 32; off > 0; off >>= 1)
        sum += __shfl_xor(sum, off, 64);

    // wave-uniform bp geometry (all lanes compute the same bits)
    const float P1v[3] = { p1x, p1y, p1z };
    const float DVv[3] = { dxv, dyv, dzv };
    const float A  = (P1v[QS] + 100.0f)*0.8f - 0.5f;
    const float B  = DVv[QS]*0.8f;
    const float AR = (P1v[QR] + 100.0f)*0.8f - 0.5f;
    const float BR = DVv[QR]*0.8f;
    const float AC = (P1v[QC] + 100.0f)*0.8f - 0.5f;
    const float BC = DVv[QC]*0.8f;

    if (lane == 0) {
        const float cb = 9.0f * step * step * sum;   // KW*(KW*step*sum)*step
        contrib[lor] = cb;
        if (params) {
            float4 a, b;
            a.x = A;  a.y = B;  a.z = AR; a.w = BR;
            b.x = AC; b.y = BC; b.z = cb; b.w = 0.0f;
            params[lor].a = a;
            params[lor].b = b;
        }
    }

    if (cnt) {
        int plo, phi; plane_range(A, B, plo, phi);
        const float rB = frcp(B);
        for (int p = plo + lane; p <= phi; p += 64) {
            int lo0, n0, lo1, n1;
            halves_for(A, B, rB, p, AR, BR, lo0, n0, lo1, n1);
            if (n0 > 0) atomicAdd(&cnt[p*2    ], (n0 + 7) >> 3);
            if (n1 > 0) atomicAdd(&cnt[p*2 + 1], (n1 + 7) >> 3);
        }
    }
}

__global__ __launch_bounds__(256) void proj_all(
    const float* __restrict__ img,
    const float* __restrict__ xl, const float* __restrict__ yl,
    const float* __restrict__ zl,
    float* __restrict__ cz, float* __restrict__ cx, float* __restrict__ cy,
    RayParam* __restrict__ params, int* __restrict__ totals)
{
    __shared__ int cnt[NBINS];
    const bool counting = (params != nullptr);
    if (counting) {
        for (int i = threadIdx.x; i < NBINS; i += 256) cnt[i] = 0;
        __syncthreads();
    }
    int* cp = counting ? cnt : nullptr;

    const int bx = blockIdx.x;
    if (blockIdx.y == 0)
        proj_body<0,1,2, 0,1,2>(img, zl, cz, params ? params        : nullptr, cp, GSQ, G, bx);
    else if (blockIdx.y == 1)
        proj_body<1,2,0, 1,2,0>(img, xl, cx, params ? params +   NL : nullptr, cp, GSQ, G, bx);
    else
        proj_body<0,1,2, 1,0,2>(img, yl, cy, params ? params + 2*NL : nullptr, cp, G, GSQ, bx);

    if (counting) {
        __syncthreads();
        for (int i = threadIdx.x; i < NBINS; i += 256)
            if (cnt[i]) atomicAdd(&totals[i], cnt[i]);
    }
}

// ---------------- K2: tiny scan of 320 totals -> offsets + cursors ----------------
__global__ __launch_bounds__(512) void scan320(
    const int* __restrict__ totals, int* __restrict__ offsets,
    int* __restrict__ cur)
{
    __shared__ int v[NBINS];
    const int tid = threadIdx.x;
    int mine = 0;
    if (tid < NBINS) { mine = totals[tid]; v[tid] = mine; }
    __syncthreads();
    for (int off = 1; off < NBINS; off <<= 1) {
        int x = 0;
        if (tid < NBINS && tid >= off) x = v[tid - off];
        __syncthreads();
        if (tid < NBINS) v[tid] += x;
        __syncthreads();
    }
    if (tid < NBINS) {
        const int excl = v[tid] - mine;
        offsets[tid] = excl;
        cur[tid]     = excl;
    }
    if (tid == 0) offsets[NBINS] = v[NBINS-1];
}

// ---------------- K3: fused reserve + write ----------------
// entry u32: ray[0:17) | s0[17:24) | (n-1)[24:27) | pass[27:29)
__global__ __launch_bounds__(256) void bin_write(
    const RayParam* __restrict__ params, int* __restrict__ cur,
    unsigned* __restrict__ entries)
{
    const int rb = blockIdx.x, pass = blockIdx.y;
    __shared__ int cnt[NBINS];
    __shared__ int base[NBINS];
    for (int i = threadIdx.x; i < NBINS; i += 256) cnt[i] = 0;
    __syncthreads();

    const int r = rb*256 + threadIdx.x;
    float A = 0, B = 0, AR = 0, BR = 0, rB = 0;
    int plo = 0, phi = -1;
    if (r < NL) {
        const float4 a = params[pass*NL + r].a;
        A = a.x; B = a.y; AR = a.z; BR = a.w;
        plane_range(A, B, plo, phi);
        rB = frcp(B);
        for (int p = plo; p <= phi; ++p) {
            int lo0, n0, lo1, n1;
            halves_for(A, B, rB, p, AR, BR, lo0, n0, lo1, n1);
            if (n0 > 0) atomicAdd(&cnt[p*2    ], (n0 + 7) >> 3);
            if (n1 > 0) atomicAdd(&cnt[p*2 + 1], (n1 + 7) >> 3);
        }
    }
    __syncthreads();
    // reserve this WG's chunk per bin via global cursor
    for (int i = threadIdx.x; i < NBINS; i += 256) {
        const int c = cnt[i];
        base[i] = c ? atomicAdd(&cur[i], c) : 0;
    }
    __syncthreads();
    for (int i = threadIdx.x; i < NBINS; i += 256) cnt[i] = 0;  // reuse as local cursor
    __syncthreads();

    if (r < NL) {
        for (int p = plo; p <= phi; ++p) {
            int lo0, n0, lo1, n1;
            halves_for(A, B, rB, p, AR, BR, lo0, n0, lo1, n1);
            #pragma unroll
            for (int h = 0; h < 2; ++h) {
                const int lo = h ? lo1 : lo0;
                const int n  = h ? n1  : n0;
                if (n > 0) {
                    const int bin = p*2 + h;
                    const int ke = (n + 7) >> 3;
                    const int gb = base[bin] + atomicAdd(&cnt[bin], ke);
                    for (int e = 0; e < ke; ++e) {
                        const int s0 = lo + e*8;
                        const int nn = (n - e*8) < 8 ? (n - e*8) : 8;
                        const unsigned enc = (unsigned)r | ((unsigned)s0 << 17)
                                           | ((unsigned)(nn-1) << 24)
                                           | ((unsigned)pass << 27);
                        if (gb + e < ENT_CAP) entries[gb + e] = enc;
                    }
                }
            }
        }
    }
}

// ---------------- bp: strided entries + edge-carry merge (r16) ----------------
__global__ __launch_bounds__(512) void bp_half(
    const RayParam* __restrict__ params, const int* __restrict__ offsets,
    const unsigned* __restrict__ entries,
    float* __restrict__ out)
{
    __shared__ float tile[81*G];    // 51840 B -> 3 WGs/CU
    const int b   = blockIdx.x;     // bin: p*2 + h
    const int c   = blockIdx.y;     // chunk 0..2
    const int p   = b >> 1;
    const int h   = b & 1;
    const int tid = threadIdx.x;
    const int rowbase = 80 * h;

    for (int j = tid; j < 81*G; j += 512) tile[j] = 0.0f;
    __syncthreads();

    int s0 = offsets[b];
    int e0 = offsets[b+1];
    if (e0 > ENT_CAP) e0 = ENT_CAP;
    if (s0 > e0) s0 = e0;
    const int n  = e0 - s0;
    const int cs = s0 + (int)(((long long)n *  c     ) / 3);
    const int ce = s0 + (int)(((long long)n * (c + 1)) / 3);

    int e = cs + tid;
    unsigned enc = 0; RayParam rp;
    if (e < ce) {
        enc = entries[e];
        rp  = params[(enc >> 27)*NL + (enc & 0x1FFFF)];
    }

    // pending merged cell: key = rl*G + ic (or -1), accumulators a00..a11
    int   pk  = -1;
    float a00 = 0.0f, a01 = 0.0f, a10 = 0.0f, a11 = 0.0f;

    while (e < ce) {
        const int en = e + 512;
        unsigned encN = 0;
        if (en < ce) encN = entries[en];   // prefetch next entry word

        const int ss = (enc >> 17) & 0x7F;
        const int nn = ((enc >> 24) & 0x7) + 1;
        const float A = rp.a.x, B = rp.a.y, AR = rp.a.z, BR = rp.a.w;
        const float AC = rp.b.x, BC = rp.b.y, cb = rp.b.z;

        for (int i = 0; i < nn; ++i) {
            const float t = ((float)(ss + i) + 0.5f) * (1.0f/NS);
            float fA = A + B*t;
            fA = fminf(fmaxf(fA, 0.0f), 159.0f);
            int ia = (int)fA; ia = ia > 158 ? 158 : ia;
            const float wa = fA - (float)ia;
            float fa;
            if (ia == p)          fa = 1.0f - wa;
            else if (ia == p - 1) fa = wa;
            else                  fa = -1.0f;

            float fR = AR + BR*t;
            fR = fminf(fmaxf(fR, 0.0f), 159.0f);
            int ib = (int)fR; ib = ib > 158 ? 158 : ib;
            const int rl = ib - rowbase;              // exact half test

            if (fa >= 0.0f && rl >= 0 && rl <= 79) {
                float fC = AC + BC*t;
                fC = fminf(fmaxf(fC, 0.0f), 159.0f);
                int ic = (int)fC; ic = ic > 158 ? 158 : ic;
                const float wb = fR - (float)ib;
                const float wc = fC - (float)ic;
                const float v  = fa * cb;
                const float v0 = v * (1.0f - wb), v1 = v * wb;
                const int key = rl*G + ic;
                if (key != pk) {
                    if (pk >= 0) {
                        float* q = tile + pk;
                        const int d = key - pk;
                        if (d == 1) {            // step right: carry right col
                            lds_add(q,     a00);
                            lds_add(q + G, a10);
                            a00 = a01; a10 = a11; a01 = 0.0f; a11 = 0.0f;
                        } else if (d == -1) {    // step left: carry left col
                            lds_add(q + 1,     a01);
                            lds_add(q + G + 1, a11);
                            a01 = a00; a11 = a10; a00 = 0.0f; a10 = 0.0f;
                        } else if (d == G) {     // step down: carry bottom row
                            lds_add(q,     a00);
                            lds_add(q + 1, a01);
                            a00 = a10; a01 = a11; a10 = 0.0f; a11 = 0.0f;
                        } else if (d == -G) {    // step up: carry top row
                            lds_add(q + G,     a10);
                            lds_add(q + G + 1, a11);
                            a10 = a00; a11 = a01; a00 = 0.0f; a01 = 0.0f;
                        } else {                 // generic: flush all
                            lds_add(q,         a00);
                            lds_add(q + 1,     a01);
                            lds_add(q + G,     a10);
                            lds_add(q + G + 1, a11);
                            a00 = 0.0f; a01 = 0.0f; a10 = 0.0f; a11 = 0.0f;
                        }
                    }
                    pk = key;
                }
                a00 += v0 * (1.0f - wc);
                a01 += v0 * wc;
                a10 += v1 * (1.0f - wc);
                a11 += v1 * wc;
            }
        }

        if (en < ce)
            rp = params[(encN >> 27)*NL + (encN & 0x1FFFF)];
        enc = encN; e = en;
    }

    // flush pending cell
    if (pk >= 0) {
        float* q = tile + pk;
        lds_add(q,         a00);
        lds_add(q + 1,     a01);
        lds_add(q + G,     a10);
        lds_add(q + G + 1, a11);
    }
    __syncthreads();

    const int nrows = h ? 80 : 81;
    float* dst = out + (size_t)p * GSQ + (size_t)rowbase * G;
    for (int j = tid; j < nrows*G; j += 512) {
#if __has_builtin(__builtin_amdgcn_global_atomic_fadd_f32)
        unsafeAtomicAdd(&dst[j], tile[j]);
#else
        atomicAdd(&dst[j], tile[j]);
#endif
    }
}

// finalize: out *= img * eff (in place)
__global__ __launch_bounds__(256) void finalize_mul(
    const float4* __restrict__ img, const float4* __restrict__ eff,
    float4* __restrict__ out)
{
    const int i = blockIdx.x * 256 + threadIdx.x;   // over GCUBE/4
    const float4 a = img[i];
    const float4 e = eff[i];
    float4 o = out[i];
    o.x *= a.x * e.x;
    o.y *= a.y * e.y;
    o.z *= a.z * e.z;
    o.w *= a.w * e.w;
    out[i] = o;
}

// ---------------- fallback: fused per-plane scan (round-6, proven) ----------------
template<int PS, int PR, int PC2>
__device__ __forceinline__ void slab_accum(
    float* __restrict__ plane,
    const float* __restrict__ lors,
    const float* __restrict__ contrib,
    int p, int wave, int lane, int nwaves)
{
    for (int base = wave*64; base < NL; base += nwaves*64) {
        const int r = base + lane;
        float A = 0.f, B = 0.f, AR = 0.f, BR = 0.f, AC = 0.f, BC = 0.f, cb = 0.f;
        int slo = 0, cnt = 0;
        if (r < NL) {
            const float q0 = lors[0*NL + r], q1 = lors[1*NL + r], q2 = lors[2*NL + r];
            const float d0 = lors[3*NL + r] - q0;
            const float d1 = lors[4*NL + r] - q1;
            const float d2 = lors[5*NL + r] - q2;
            const float P1[3] = { q0, q1, q2 };
            const float DV[3] = { d0, d1, d2 };
            A  = (P1[PS]  + 100.0f)*0.8f - 0.5f;  B  = DV[PS]*0.8f;
            AR = (P1[PR]  + 100.0f)*0.8f - 0.5f;  BR = DV[PR]*0.8f;
            AC = (P1[PC2] + 100.0f)*0.8f - 0.5f;  BC = DV[PC2]*0.8f;
            cb = contrib[r];
            const float rB = frcp(B);
            cnt = cnt_for(A, B, rB, p, slo);
            if (cnt < 0) cnt = 0;
        }

        int pref = cnt;
        #pragma unroll
        for (int off = 1; off < 64; off <<= 1) {
            const int nsh = __shfl_up(pref, off, 64);
            if (lane >= off) pref += nsh;
        }
        const int total = __shfl(pref, 63, 64);
        const int start = pref - cnt;

        for (int k0 = 0; k0 < total; k0 += 64) {
            const int k  = k0 + lane;
            const int kc = k < total ? k : total - 1;

            int j = 0;
            #pragma unroll
            for (int stp = 32; stp >= 1; stp >>= 1) {
                const int cand = j + stp;
                const int sc = __shfl(start, cand, 64);
                if (cand < 64 && sc <= kc) j = cand;
            }

            const int   sj  = __shfl(slo,   j, 64);
            const int   stj = __shfl(start, j, 64);
            const float Aj  = __shfl(A,  j, 64);
            const float Bj  = __shfl(B,  j, 64);
            const float ARj = __shfl(AR, j, 64);
            const float BRj = __shfl(BR, j, 64);
            const float ACj = __shfl(AC, j, 64);
            const float BCj = __shfl(BC, j, 64);
            const float cbj = __shfl(cb, j, 64);

            const int s = sj + (kc - stj);
            const float t = ((float)s + 0.5f) * (1.0f/NS);
            float fA = Aj + Bj * t;
            fA = fminf(fmaxf(fA, 0.0f), 159.0f);
            int ia = (int)fA; ia = ia > 158 ? 158 : ia;
            const float wa = fA - (float)ia;
            float fa;
            if (ia == p)          fa = 1.0f - wa;
            else if (ia == p - 1) fa = wa;
            else                  fa = -1.0f;

            float fR = ARj + BRj * t;
            float fC = ACj + BCj * t;
            fR = fminf(fmaxf(fR, 0.0f), 159.0f);
            fC = fminf(fmaxf(fC, 0.0f), 159.0f);
            int ib = (int)fR; ib = ib > 158 ? 158 : ib;
            int ic = (int)fC; ic = ic > 158 ? 158 : ic;
            const float wb = fR - (float)ib;
            const float wc = fC - (float)ic;

            if (k < total && fa >= 0.0f) {
                const float v  = fa * cbj;
                const float v0 = v * (1.0f - wb), v1 = v * wb;
                float* q = plane + ib*G + ic;
                lds_add(q,         v0 * (1.0f - wc));
                lds_add(q + 1,     v0 * wc);
                lds_add(q + G,     v1 * (1.0f - wc));
                lds_add(q + G + 1, v1 * wc);
            }
        }
    }
}

__global__ __launch_bounds__(1024) void bp_fused(
    const float* __restrict__ img, const float* __restrict__ eff,
    const float* __restrict__ zl, const float* __restrict__ xl,
    const float* __restrict__ yl,
    const float* __restrict__ cz, const float* __restrict__ cx,
    const float* __restrict__ cy,
    float* __restrict__ out)
{
    __shared__ float plane[GSQ];
    const int p    = blockIdx.x;
    const int tid  = threadIdx.x;
    const int wave = tid >> 6;
    const int lane = tid & 63;

    for (int j = tid; j < GSQ; j += 1024) plane[j] = 0.0f;
    __syncthreads();

    slab_accum<0,1,2>(plane, zl, cz, p, wave, lane, 16);
    slab_accum<1,2,0>(plane, xl, cx, p, wave, lane, 16);
    slab_accum<1,0,2>(plane, yl, cy, p, wave, lane, 16);

    __syncthreads();

    const int pbase = p * GSQ;
    for (int j = tid; j < GSQ; j += 1024) {
        const int idx = pbase + j;
        out[idx] = plane[j] * img[idx] * eff[idx];
    }
}

extern "C" void kernel_launch(void* const* d_in, const int* in_sizes, int n_in,
                              void* d_out, int out_size, void* d_ws, size_t ws_size,
                              hipStream_t stream) {
    const float* img = (const float*)d_in[0];
    const float* eff = (const float*)d_in[1];
    const float* xl  = (const float*)d_in[2];
    const float* yl  = (const float*)d_in[3];
    const float* zl  = (const float*)d_in[4];
    float* out = (float*)d_out;

    const size_t CONTRIB_B = (size_t)3*NL*sizeof(float);       //   600 KB
    const size_t PARAMS_B  = (size_t)3*NL*sizeof(RayParam);    //   4.8 MB
    const size_t TOT_B     = (size_t)NBINS*sizeof(int);        //  1.25 KB
    const size_t OFFS_B    = (size_t)(NBINS+1)*sizeof(int);
    const size_t CUR_B     = (size_t)NBINS*sizeof(int);
    const size_t ENT_B     = (size_t)ENT_CAP*sizeof(unsigned); //    46 MB

    char* w = (char*)d_ws;
    float*    cz      = (float*)w;
    float*    cx      = cz + NL;
    float*    cy      = cx + NL;
    RayParam* params  = (RayParam*)(w + CONTRIB_B);
    int*      totals  = (int*)(w + CONTRIB_B + PARAMS_B);
    int*      offsets = (int*)(w + CONTRIB_B + PARAMS_B + TOT_B);
    int*      cur     = (int*)(w + CONTRIB_B + PARAMS_B + TOT_B + OFFS_B);
    unsigned* entries = (unsigned*)(w + CONTRIB_B + PARAMS_B + TOT_B + OFFS_B + CUR_B);

    const bool binned =
        ws_size >= CONTRIB_B + PARAMS_B + TOT_B + OFFS_B + CUR_B + ENT_B;  // ~51.4 MB

    if (binned) {
        hipMemsetAsync(totals, 0, TOT_B, stream);
        hipMemsetAsync(out, 0, (size_t)GCUBE * sizeof(float), stream);
    }

    proj_all<<<dim3(NL/4, 3), dim3(256), 0, stream>>>(
        img, xl, yl, zl, cz, cx, cy, binned ? params : nullptr,
        binned ? totals : nullptr);

    if (binned) {
        scan320  <<<dim3(1),      dim3(512), 0, stream>>>(totals, offsets, cur);
        bin_write<<<dim3(NRB, 3), dim3(256), 0, stream>>>(params, cur, entries);
        bp_half  <<<dim3(NBINS,3),dim3(512), 0, stream>>>(params, offsets, entries, out);
        finalize_mul<<<dim3(GCUBE/4/256), dim3(256), 0, stream>>>(
            (const float4*)img, (const float4*)eff, (float4*)out);
    } else {
        bp_fused<<<dim3(G), dim3(1024), 0, stream>>>(
            img, eff, zl, xl, yl, cz, cx, cy, out);
    }
}

// Round 18
// 1213.569 us; speedup vs baseline: 1.2762x; 1.2762x over previous
//
#include <hip/hip_runtime.h>

#define NL 50000
#define NS 128
#define G 160
#define GSQ (160*160)
#define GCUBE (160*160*160)
#define NRB 196             // bin_write ray blocks of 256
#define NRB2 782            // proj WGs: 64 rays each (782*64 = 50048 >= NL)
#define NBINS (G*2)         // (plane, row-half) bins = 320
#define ENT_CAP 11500000

struct RayParam { float4 a, b; };  // a={A,B,AR,BR}  b={AC,BC,cb,pad}

__device__ __forceinline__ void lds_add(float* p, float v) {
    atomicAdd(p, v);   // non-returning ds_add_f32
}

__device__ __forceinline__ float frcp(float x) {
#if __has_builtin(__builtin_amdgcn_rcpf)
    return __builtin_amdgcn_rcpf(x);
#else
    return 1.0f / x;
#endif
}

// f -> (base index, frac weight); identical math to reference.
__device__ __forceinline__ void coordf(float pos, int& i, float& w) {
    float f = (pos + 100.0f) * 0.8f - 0.5f;
    f = fminf(fmaxf(f, 0.0f), 159.0f);
    int ii = (int)f; ii = ii > 158 ? 158 : ii;
    i = ii; w = f - (float)ii;
}

// Padded sample window for (slab line f=A+B*t, plane p). Same in count/write;
// bp's fa>=0 recheck filters the padding.
__device__ __forceinline__ int cnt_for(float A, float B, float rB, int p, int& slo_out) {
    const float glo = (p <= 1)   ? -1.0f  : (float)(p - 1);
    const float ghi = (p >= 158) ? 160.0f : (float)(p + 1);
    int slo, shi;
    if (B == 0.0f) {
        if (A < glo || A > ghi) { slo_out = 0; return 0; }
        slo = 0; shi = NS - 1;
    } else {
        const float t1 = (glo - A) * rB, t2 = (ghi - A) * rB;
        const float tlo = fminf(t1, t2), thi = fmaxf(t1, t2);
        float slof = ceilf (tlo * (float)NS - 0.75f);
        float shif = floorf(thi * (float)NS - 0.25f);
        slof = fminf(fmaxf(slof,  0.0f), 127.0f);
        shif = fminf(fmaxf(shif, -1.0f), 127.0f);
        slo = (int)slof; shi = (int)shif;
    }
    slo_out = slo;
    return shi - slo + 1;   // may be <= 0
}

// Split the (ray,plane) window into row-half sub-windows (conservative +-1
// sample overlap at the fR=80 crossing; bp rechecks ib-half exactly). [r11]
__device__ __forceinline__ void halves_for(
    float A, float B, float rB, int p, float AR, float BR,
    int& lo0, int& n0, int& lo1, int& n1)
{
    lo0 = lo1 = 0; n0 = n1 = 0;
    int slo; const int c = cnt_for(A, B, rB, p, slo);
    if (c <= 0) return;
    const int shi = slo + c - 1;
    if (BR == 0.0f) {
        if (AR < 80.0f) { lo0 = slo; n0 = c; } else { lo1 = slo; n1 = c; }
        return;
    }
    float sstar = ((80.0f - AR) * frcp(BR)) * (float)NS - 0.5f;
    sstar = fminf(fmaxf(sstar, -300.0f), 300.0f);
    float lo0f, hi0f, lo1f, hi1f;
    if (BR > 0.0f) {   // fR rising: low-s side is half0
        lo0f = (float)slo;  hi0f = fminf((float)shi, floorf(sstar) + 1.0f);
        lo1f = fmaxf((float)slo, ceilf(sstar) - 1.0f);  hi1f = (float)shi;
    } else {
        lo1f = (float)slo;  hi1f = fminf((float)shi, floorf(sstar) + 1.0f);
        lo0f = fmaxf((float)slo, ceilf(sstar) - 1.0f);  hi0f = (float)shi;
    }
    lo0 = (int)lo0f; n0 = (int)hi0f - lo0 + 1; if (n0 < 0) n0 = 0;
    lo1 = (int)lo1f; n1 = (int)hi1f - lo1 + 1; if (n1 < 0) n1 = 0;
}

__device__ __forceinline__ void plane_range(float A, float B, int& plo, int& phi) {
    const float f0 = A + B * (0.5f / NS);
    const float f1 = A + B * (((float)NS - 0.5f) / NS);
    const float fmn = fminf(f0, f1), fmx = fmaxf(f0, f1);
    plo = (int)fmaxf(ceilf (fmn - 1.01f), 0.0f);
    phi = (int)fminf(floorf(fmx + 1.01f), 159.0f);
}

// ---------------- Stage 1: projection + params + fused count (per ray) ----------------
template<int PA, int PB, int PC, int QS, int QR, int QC>
__device__ __forceinline__ void proj_body(
    const float* __restrict__ img,
    const float* __restrict__ lors,
    float* __restrict__ contrib,
    RayParam* __restrict__ params,
    int* __restrict__ cnt,              // LDS histogram (or nullptr)
    int sa, int sb, int lor)
{
    const int lane = threadIdx.x & 63;

    const float p1x = lors[0*NL + lor];
    const float p1y = lors[1*NL + lor];
    const float p1z = lors[2*NL + lor];
    const float dxv = lors[3*NL + lor] - p1x;
    const float dyv = lors[4*NL + lor] - p1y;
    const float dzv = lors[5*NL + lor] - p1z;
    const float len  = sqrtf(dxv*dxv + dyv*dyv + dzv*dzv);
    const float step = len * (1.0f/NS);

    float2 P00[2], P01[2], P10[2], P11[2];
    float waq[2], wbq[2], wcq[2];

    #pragma unroll
    for (int q = 0; q < 2; ++q) {
        const int s = lane + q*64;
        const float t = ((float)s + 0.5f) * (1.0f/NS);
        const float pos[3] = { p1x + t*dxv, p1y + t*dyv, p1z + t*dzv };
        int ia, ib, ic; float wa, wb, wc;
        coordf(pos[PA], ia, wa);
        coordf(pos[PB], ib, wb);
        coordf(pos[PC], ic, wc);
        const float* g = img + ia*sa + ib*sb + ic;
        __builtin_memcpy(&P00[q], g,            8);
        __builtin_memcpy(&P01[q], g + sb,       8);
        __builtin_memcpy(&P10[q], g + sa,       8);
        __builtin_memcpy(&P11[q], g + sa + sb,  8);
        waq[q] = wa; wbq[q] = wb; wcq[q] = wc;
    }

    float sum = 0.0f;
    #pragma unroll
    for (int q = 0; q < 2; ++q) {
        const float wa = waq[q], wb = wbq[q], wc = wcq[q];
        const float c00 = P00[q].x + wc*(P00[q].y - P00[q].x);
        const float c01 = P01[q].x + wc*(P01[q].y - P01[q].x);
        const float c10 = P10[q].x + wc*(P10[q].y - P10[q].x);
        const float c11 = P11[q].x + wc*(P11[q].y - P11[q].x);
        const float c0  = c00 + wb*(c01 - c00);
        const float c1  = c10 + wb*(c11 - c10);
        sum += c0 + wa*(c1 - c0);
    }

    #pragma unroll
    for (int off = 32; off > 0; off >>= 1)
        sum += __shfl_xor(sum, off, 64);

    // wave-uniform bp geometry (all lanes compute the same bits)
    const float P1v[3] = { p1x, p1y, p1z };
    const float DVv[3] = { dxv, dyv, dzv };
    const float A  = (P1v[QS] + 100.0f)*0.8f - 0.5f;
    const float B  = DVv[QS]*0.8f;
    const float AR = (P1v[QR] + 100.0f)*0.8f - 0.5f;
    const float BR = DVv[QR]*0.8f;
    const float AC = (P1v[QC] + 100.0f)*0.8f - 0.5f;
    const float BC = DVv[QC]*0.8f;

    if (lane == 0) {
        const float cb = 9.0f * step * step * sum;   // KW*(KW*step*sum)*step
        contrib[lor] = cb;
        if (params) {
            float4 a, b;
            a.x = A;  a.y = B;  a.z = AR; a.w = BR;
            b.x = AC; b.y = BC; b.z = cb; b.w = 0.0f;
            params[lor].a = a;
            params[lor].b = b;
        }
    }

    if (cnt) {
        int plo, phi; plane_range(A, B, plo, phi);
        const float rB = frcp(B);
        for (int p = plo + lane; p <= phi; p += 64) {
            int lo0, n0, lo1, n1;
            halves_for(A, B, rB, p, AR, BR, lo0, n0, lo1, n1);
            if (n0 > 0) atomicAdd(&cnt[p*2    ], (n0 + 7) >> 3);
            if (n1 > 0) atomicAdd(&cnt[p*2 + 1], (n1 + 7) >> 3);
        }
    }
}

// 64 rays per WG: each of the 4 waves loops 16 consecutive rays. One
// histogram flush per WG -> ~750K global atomics total (r17's 4-ray WGs
// produced ~11M on 320 hot ints = the +400us regression).
__global__ __launch_bounds__(256) void proj_all(
    const float* __restrict__ img,
    const float* __restrict__ xl, const float* __restrict__ yl,
    const float* __restrict__ zl,
    float* __restrict__ cz, float* __restrict__ cx, float* __restrict__ cy,
    RayParam* __restrict__ params, int* __restrict__ totals)
{
    __shared__ int cnt[NBINS];
    const bool counting = (params != nullptr);
    if (counting) {
        for (int i = threadIdx.x; i < NBINS; i += 256) cnt[i] = 0;
        __syncthreads();
    }
    int* cp = counting ? cnt : nullptr;

    const int wave = threadIdx.x >> 6;
    const int base = blockIdx.x * 64 + wave * 16;

    if (blockIdx.y == 0) {
        for (int it = 0; it < 16; ++it) {
            const int lor = base + it;
            if (lor < NL)
                proj_body<0,1,2, 0,1,2>(img, zl, cz, params ? params : nullptr, cp, GSQ, G, lor);
        }
    } else if (blockIdx.y == 1) {
        for (int it = 0; it < 16; ++it) {
            const int lor = base + it;
            if (lor < NL)
                proj_body<1,2,0, 1,2,0>(img, xl, cx, params ? params + NL : nullptr, cp, GSQ, G, lor);
        }
    } else {
        for (int it = 0; it < 16; ++it) {
            const int lor = base + it;
            if (lor < NL)
                proj_body<0,1,2, 1,0,2>(img, yl, cy, params ? params + 2*NL : nullptr, cp, G, GSQ, lor);
        }
    }

    if (counting) {
        __syncthreads();
        for (int i = threadIdx.x; i < NBINS; i += 256)
            if (cnt[i]) atomicAdd(&totals[i], cnt[i]);
    }
}

// ---------------- K2: tiny scan of 320 totals -> offsets + cursors ----------------
__global__ __launch_bounds__(512) void scan320(
    const int* __restrict__ totals, int* __restrict__ offsets,
    int* __restrict__ cur)
{
    __shared__ int v[NBINS];
    const int tid = threadIdx.x;
    int mine = 0;
    if (tid < NBINS) { mine = totals[tid]; v[tid] = mine; }
    __syncthreads();
    for (int off = 1; off < NBINS; off <<= 1) {
        int x = 0;
        if (tid < NBINS && tid >= off) x = v[tid - off];
        __syncthreads();
        if (tid < NBINS) v[tid] += x;
        __syncthreads();
    }
    if (tid < NBINS) {
        const int excl = v[tid] - mine;
        offsets[tid] = excl;
        cur[tid]     = excl;
    }
    if (tid == 0) offsets[NBINS] = v[NBINS-1];
}

// ---------------- K3: fused reserve + write ----------------
// entry u32: ray[0:17) | s0[17:24) | (n-1)[24:27) | pass[27:29)
__global__ __launch_bounds__(256) void bin_write(
    const RayParam* __restrict__ params, int* __restrict__ cur,
    unsigned* __restrict__ entries)
{
    const int rb = blockIdx.x, pass = blockIdx.y;
    __shared__ int cnt[NBINS];
    __shared__ int base[NBINS];
    for (int i = threadIdx.x; i < NBINS; i += 256) cnt[i] = 0;
    __syncthreads();

    const int r = rb*256 + threadIdx.x;
    float A = 0, B = 0, AR = 0, BR = 0, rB = 0;
    int plo = 0, phi = -1;
    if (r < NL) {
        const float4 a = params[pass*NL + r].a;
        A = a.x; B = a.y; AR = a.z; BR = a.w;
        plane_range(A, B, plo, phi);
        rB = frcp(B);
        for (int p = plo; p <= phi; ++p) {
            int lo0, n0, lo1, n1;
            halves_for(A, B, rB, p, AR, BR, lo0, n0, lo1, n1);
            if (n0 > 0) atomicAdd(&cnt[p*2    ], (n0 + 7) >> 3);
            if (n1 > 0) atomicAdd(&cnt[p*2 + 1], (n1 + 7) >> 3);
        }
    }
    __syncthreads();
    // reserve this WG's chunk per bin via global cursor
    for (int i = threadIdx.x; i < NBINS; i += 256) {
        const int c = cnt[i];
        base[i] = c ? atomicAdd(&cur[i], c) : 0;
    }
    __syncthreads();
    for (int i = threadIdx.x; i < NBINS; i += 256) cnt[i] = 0;  // reuse as local cursor
    __syncthreads();

    if (r < NL) {
        for (int p = plo; p <= phi; ++p) {
            int lo0, n0, lo1, n1;
            halves_for(A, B, rB, p, AR, BR, lo0, n0, lo1, n1);
            #pragma unroll
            for (int h = 0; h < 2; ++h) {
                const int lo = h ? lo1 : lo0;
                const int n  = h ? n1  : n0;
                if (n > 0) {
                    const int bin = p*2 + h;
                    const int ke = (n + 7) >> 3;
                    const int gb = base[bin] + atomicAdd(&cnt[bin], ke);
                    for (int e = 0; e < ke; ++e) {
                        const int s0 = lo + e*8;
                        const int nn = (n - e*8) < 8 ? (n - e*8) : 8;
                        const unsigned enc = (unsigned)r | ((unsigned)s0 << 17)
                                           | ((unsigned)(nn-1) << 24)
                                           | ((unsigned)pass << 27);
                        if (gb + e < ENT_CAP) entries[gb + e] = enc;
                    }
                }
            }
        }
    }
}

// ---------------- bp: strided entries + edge-carry merge (r16) ----------------
__global__ __launch_bounds__(512) void bp_half(
    const RayParam* __restrict__ params, const int* __restrict__ offsets,
    const unsigned* __restrict__ entries,
    float* __restrict__ out)
{
    __shared__ float tile[81*G];    // 51840 B -> 3 WGs/CU
    const int b   = blockIdx.x;     // bin: p*2 + h
    const int c   = blockIdx.y;     // chunk 0..2
    const int p   = b >> 1;
    const int h   = b & 1;
    const int tid = threadIdx.x;
    const int rowbase = 80 * h;

    for (int j = tid; j < 81*G; j += 512) tile[j] = 0.0f;
    __syncthreads();

    int s0 = offsets[b];
    int e0 = offsets[b+1];
    if (e0 > ENT_CAP) e0 = ENT_CAP;
    if (s0 > e0) s0 = e0;
    const int n  = e0 - s0;
    const int cs = s0 + (int)(((long long)n *  c     ) / 3);
    const int ce = s0 + (int)(((long long)n * (c + 1)) / 3);

    int e = cs + tid;
    unsigned enc = 0; RayParam rp;
    if (e < ce) {
        enc = entries[e];
        rp  = params[(enc >> 27)*NL + (enc & 0x1FFFF)];
    }

    // pending merged cell: key = rl*G + ic (or -1), accumulators a00..a11
    int   pk  = -1;
    float a00 = 0.0f, a01 = 0.0f, a10 = 0.0f, a11 = 0.0f;

    while (e < ce) {
        const int en = e + 512;
        unsigned encN = 0;
        if (en < ce) encN = entries[en];   // prefetch next entry word

        const int ss = (enc >> 17) & 0x7F;
        const int nn = ((enc >> 24) & 0x7) + 1;
        const float A = rp.a.x, B = rp.a.y, AR = rp.a.z, BR = rp.a.w;
        const float AC = rp.b.x, BC = rp.b.y, cb = rp.b.z;

        for (int i = 0; i < nn; ++i) {
            const float t = ((float)(ss + i) + 0.5f) * (1.0f/NS);
            float fA = A + B*t;
            fA = fminf(fmaxf(fA, 0.0f), 159.0f);
            int ia = (int)fA; ia = ia > 158 ? 158 : ia;
            const float wa = fA - (float)ia;
            float fa;
            if (ia == p)          fa = 1.0f - wa;
            else if (ia == p - 1) fa = wa;
            else                  fa = -1.0f;

            float fR = AR + BR*t;
            fR = fminf(fmaxf(fR, 0.0f), 159.0f);
            int ib = (int)fR; ib = ib > 158 ? 158 : ib;
            const int rl = ib - rowbase;              // exact half test

            if (fa >= 0.0f && rl >= 0 && rl <= 79) {
                float fC = AC + BC*t;
                fC = fminf(fmaxf(fC, 0.0f), 159.0f);
                int ic = (int)fC; ic = ic > 158 ? 158 : ic;
                const float wb = fR - (float)ib;
                const float wc = fC - (float)ic;
                const float v  = fa * cb;
                const float v0 = v * (1.0f - wb), v1 = v * wb;
                const int key = rl*G + ic;
                if (key != pk) {
                    if (pk >= 0) {
                        float* q = tile + pk;
                        const int d = key - pk;
                        if (d == 1) {            // step right: carry right col
                            lds_add(q,     a00);
                            lds_add(q + G, a10);
                            a00 = a01; a10 = a11; a01 = 0.0f; a11 = 0.0f;
                        } else if (d == -1) {    // step left: carry left col
                            lds_add(q + 1,     a01);
                            lds_add(q + G + 1, a11);
                            a01 = a00; a11 = a10; a00 = 0.0f; a10 = 0.0f;
                        } else if (d == G) {     // step down: carry bottom row
                            lds_add(q,     a00);
                            lds_add(q + 1, a01);
                            a00 = a10; a01 = a11; a10 = 0.0f; a11 = 0.0f;
                        } else if (d == -G) {    // step up: carry top row
                            lds_add(q + G,     a10);
                            lds_add(q + G + 1, a11);
                            a10 = a00; a11 = a01; a00 = 0.0f; a01 = 0.0f;
                        } else {                 // generic: flush all
                            lds_add(q,         a00);
                            lds_add(q + 1,     a01);
                            lds_add(q + G,     a10);
                            lds_add(q + G + 1, a11);
                            a00 = 0.0f; a01 = 0.0f; a10 = 0.0f; a11 = 0.0f;
                        }
                    }
                    pk = key;
                }
                a00 += v0 * (1.0f - wc);
                a01 += v0 * wc;
                a10 += v1 * (1.0f - wc);
                a11 += v1 * wc;
            }
        }

        if (en < ce)
            rp = params[(encN >> 27)*NL + (encN & 0x1FFFF)];
        enc = encN; e = en;
    }

    // flush pending cell
    if (pk >= 0) {
        float* q = tile + pk;
        lds_add(q,         a00);
        lds_add(q + 1,     a01);
        lds_add(q + G,     a10);
        lds_add(q + G + 1, a11);
    }
    __syncthreads();

    const int nrows = h ? 80 : 81;
    float* dst = out + (size_t)p * GSQ + (size_t)rowbase * G;
    for (int j = tid; j < nrows*G; j += 512) {
#if __has_builtin(__builtin_amdgcn_global_atomic_fadd_f32)
        unsafeAtomicAdd(&dst[j], tile[j]);
#else
        atomicAdd(&dst[j], tile[j]);
#endif
    }
}

// finalize: out *= img * eff (in place)
__global__ __launch_bounds__(256) void finalize_mul(
    const float4* __restrict__ img, const float4* __restrict__ eff,
    float4* __restrict__ out)
{
    const int i = blockIdx.x * 256 + threadIdx.x;   // over GCUBE/4
    const float4 a = img[i];
    const float4 e = eff[i];
    float4 o = out[i];
    o.x *= a.x * e.x;
    o.y *= a.y * e.y;
    o.z *= a.z * e.z;
    o.w *= a.w * e.w;
    out[i] = o;
}

// ---------------- fallback: fused per-plane scan (round-6, proven) ----------------
template<int PS, int PR, int PC2>
__device__ __forceinline__ void slab_accum(
    float* __restrict__ plane,
    const float* __restrict__ lors,
    const float* __restrict__ contrib,
    int p, int wave, int lane, int nwaves)
{
    for (int base = wave*64; base < NL; base += nwaves*64) {
        const int r = base + lane;
        float A = 0.f, B = 0.f, AR = 0.f, BR = 0.f, AC = 0.f, BC = 0.f, cb = 0.f;
        int slo = 0, cnt = 0;
        if (r < NL) {
            const float q0 = lors[0*NL + r], q1 = lors[1*NL + r], q2 = lors[2*NL + r];
            const float d0 = lors[3*NL + r] - q0;
            const float d1 = lors[4*NL + r] - q1;
            const float d2 = lors[5*NL + r] - q2;
            const float P1[3] = { q0, q1, q2 };
            const float DV[3] = { d0, d1, d2 };
            A  = (P1[PS]  + 100.0f)*0.8f - 0.5f;  B  = DV[PS]*0.8f;
            AR = (P1[PR]  + 100.0f)*0.8f - 0.5f;  BR = DV[PR]*0.8f;
            AC = (P1[PC2] + 100.0f)*0.8f - 0.5f;  BC = DV[PC2]*0.8f;
            cb = contrib[r];
            const float rB = frcp(B);
            cnt = cnt_for(A, B, rB, p, slo);
            if (cnt < 0) cnt = 0;
        }

        int pref = cnt;
        #pragma unroll
        for (int off = 1; off < 64; off <<= 1) {
            const int nsh = __shfl_up(pref, off, 64);
            if (lane >= off) pref += nsh;
        }
        const int total = __shfl(pref, 63, 64);
        const int start = pref - cnt;

        for (int k0 = 0; k0 < total; k0 += 64) {
            const int k  = k0 + lane;
            const int kc = k < total ? k : total - 1;

            int j = 0;
            #pragma unroll
            for (int stp = 32; stp >= 1; stp >>= 1) {
                const int cand = j + stp;
                const int sc = __shfl(start, cand, 64);
                if (cand < 64 && sc <= kc) j = cand;
            }

            const int   sj  = __shfl(slo,   j, 64);
            const int   stj = __shfl(start, j, 64);
            const float Aj  = __shfl(A,  j, 64);
            const float Bj  = __shfl(B,  j, 64);
            const float ARj = __shfl(AR, j, 64);
            const float BRj = __shfl(BR, j, 64);
            const float ACj = __shfl(AC, j, 64);
            const float BCj = __shfl(BC, j, 64);
            const float cbj = __shfl(cb, j, 64);

            const int s = sj + (kc - stj);
            const float t = ((float)s + 0.5f) * (1.0f/NS);
            float fA = Aj + Bj * t;
            fA = fminf(fmaxf(fA, 0.0f), 159.0f);
            int ia = (int)fA; ia = ia > 158 ? 158 : ia;
            const float wa = fA - (float)ia;
            float fa;
            if (ia == p)          fa = 1.0f - wa;
            else if (ia == p - 1) fa = wa;
            else                  fa = -1.0f;

            float fR = ARj + BRj * t;
            float fC = ACj + BCj * t;
            fR = fminf(fmaxf(fR, 0.0f), 159.0f);
            fC = fminf(fmaxf(fC, 0.0f), 159.0f);
            int ib = (int)fR; ib = ib > 158 ? 158 : ib;
            int ic = (int)fC; ic = ic > 158 ? 158 : ic;
            const float wb = fR - (float)ib;
            const float wc = fC - (float)ic;

            if (k < total && fa >= 0.0f) {
                const float v  = fa * cbj;
                const float v0 = v * (1.0f - wb), v1 = v * wb;
                float* q = plane + ib*G + ic;
                lds_add(q,         v0 * (1.0f - wc));
                lds_add(q + 1,     v0 * wc);
                lds_add(q + G,     v1 * (1.0f - wc));
                lds_add(q + G + 1, v1 * wc);
            }
        }
    }
}

__global__ __launch_bounds__(1024) void bp_fused(
    const float* __restrict__ img, const float* __restrict__ eff,
    const float* __restrict__ zl, const float* __restrict__ xl,
    const float* __restrict__ yl,
    const float* __restrict__ cz, const float* __restrict__ cx,
    const float* __restrict__ cy,
    float* __restrict__ out)
{
    __shared__ float plane[GSQ];
    const int p    = blockIdx.x;
    const int tid  = threadIdx.x;
    const int wave = tid >> 6;
    const int lane = tid & 63;

    for (int j = tid; j < GSQ; j += 1024) plane[j] = 0.0f;
    __syncthreads();

    slab_accum<0,1,2>(plane, zl, cz, p, wave, lane, 16);
    slab_accum<1,2,0>(plane, xl, cx, p, wave, lane, 16);
    slab_accum<1,0,2>(plane, yl, cy, p, wave, lane, 16);

    __syncthreads();

    const int pbase = p * GSQ;
    for (int j = tid; j < GSQ; j += 1024) {
        const int idx = pbase + j;
        out[idx] = plane[j] * img[idx] * eff[idx];
    }
}

extern "C" void kernel_launch(void* const* d_in, const int* in_sizes, int n_in,
                              void* d_out, int out_size, void* d_ws, size_t ws_size,
                              hipStream_t stream) {
    const float* img = (const float*)d_in[0];
    const float* eff = (const float*)d_in[1];
    const float* xl  = (const float*)d_in[2];
    const float* yl  = (const float*)d_in[3];
    const float* zl  = (const float*)d_in[4];
    float* out = (float*)d_out;

    const size_t CONTRIB_B = (size_t)3*NL*sizeof(float);       //   600 KB
    const size_t PARAMS_B  = (size_t)3*NL*sizeof(RayParam);    //   4.8 MB
    const size_t TOT_B     = (size_t)NBINS*sizeof(int);        //  1.25 KB
    const size_t OFFS_B    = (size_t)(NBINS+1)*sizeof(int);
    const size_t CUR_B     = (size_t)NBINS*sizeof(int);
    const size_t ENT_B     = (size_t)ENT_CAP*sizeof(unsigned); //    46 MB

    char* w = (char*)d_ws;
    float*    cz      = (float*)w;
    float*    cx      = cz + NL;
    float*    cy      = cx + NL;
    RayParam* params  = (RayParam*)(w + CONTRIB_B);
    int*      totals  = (int*)(w + CONTRIB_B + PARAMS_B);
    int*      offsets = (int*)(w + CONTRIB_B + PARAMS_B + TOT_B);
    int*      cur     = (int*)(w + CONTRIB_B + PARAMS_B + TOT_B + OFFS_B);
    unsigned* entries = (unsigned*)(w + CONTRIB_B + PARAMS_B + TOT_B + OFFS_B + CUR_B);

    const bool binned =
        ws_size >= CONTRIB_B + PARAMS_B + TOT_B + OFFS_B + CUR_B + ENT_B;  // ~51.4 MB

    if (binned) {
        hipMemsetAsync(totals, 0, TOT_B, stream);
        hipMemsetAsync(out, 0, (size_t)GCUBE * sizeof(float), stream);
    }

    proj_all<<<dim3(NRB2, 3), dim3(256), 0, stream>>>(
        img, xl, yl, zl, cz, cx, cy, binned ? params : nullptr,
        binned ? totals : nullptr);

    if (binned) {
        scan320  <<<dim3(1),      dim3(512), 0, stream>>>(totals, offsets, cur);
        bin_write<<<dim3(NRB, 3), dim3(256), 0, stream>>>(params, cur, entries);
        bp_half  <<<dim3(NBINS,3),dim3(512), 0, stream>>>(params, offsets, entries, out);
        finalize_mul<<<dim3(GCUBE/4/256), dim3(256), 0, stream>>>(
            (const float4*)img, (const float4*)eff, (float4*)out);
    } else {
        bp_fused<<<dim3(G), dim3(1024), 0, stream>>>(
            img, eff, zl, xl, yl, cz, cx, cy, out);
    }
}

// Round 19
// 1116.800 us; speedup vs baseline: 1.3868x; 1.0866x over previous
//
#include <hip/hip_runtime.h>

#define NL 50000
#define NS 128
#define G 160
#define GSQ (160*160)
#define GCUBE (160*160*160)
#define NRB 196             // bin_write ray blocks of 256
#define NRB2 782            // proj WGs: 64 rays each (782*64 = 50048 >= NL)
#define NBINS (G*2)         // (plane, row-half) bins = 320
#define ENT_CAP 11500000

struct RayParam { float4 a, b; };  // a={A,B,AR,BR}  b={AC,BC,cb,pad}

__device__ __forceinline__ void lds_add(float* p, float v) {
    atomicAdd(p, v);   // non-returning ds_add_f32
}

__device__ __forceinline__ float frcp(float x) {
#if __has_builtin(__builtin_amdgcn_rcpf)
    return __builtin_amdgcn_rcpf(x);
#else
    return 1.0f / x;
#endif
}

// f -> (base index, frac weight); identical math to reference.
__device__ __forceinline__ void coordf(float pos, int& i, float& w) {
    float f = (pos + 100.0f) * 0.8f - 0.5f;
    f = fminf(fmaxf(f, 0.0f), 159.0f);
    int ii = (int)f; ii = ii > 158 ? 158 : ii;
    i = ii; w = f - (float)ii;
}

// Padded sample window for (slab line f=A+B*t, plane p). Same in count/write;
// bp's fa>=0 recheck filters the padding.
__device__ __forceinline__ int cnt_for(float A, float B, float rB, int p, int& slo_out) {
    const float glo = (p <= 1)   ? -1.0f  : (float)(p - 1);
    const float ghi = (p >= 158) ? 160.0f : (float)(p + 1);
    int slo, shi;
    if (B == 0.0f) {
        if (A < glo || A > ghi) { slo_out = 0; return 0; }
        slo = 0; shi = NS - 1;
    } else {
        const float t1 = (glo - A) * rB, t2 = (ghi - A) * rB;
        const float tlo = fminf(t1, t2), thi = fmaxf(t1, t2);
        float slof = ceilf (tlo * (float)NS - 0.75f);
        float shif = floorf(thi * (float)NS - 0.25f);
        slof = fminf(fmaxf(slof,  0.0f), 127.0f);
        shif = fminf(fmaxf(shif, -1.0f), 127.0f);
        slo = (int)slof; shi = (int)shif;
    }
    slo_out = slo;
    return shi - slo + 1;   // may be <= 0
}

// Split the (ray,plane) window into row-half sub-windows (conservative +-1
// sample overlap at the fR=80 crossing; bp rechecks ib-half exactly). [r11]
__device__ __forceinline__ void halves_for(
    float A, float B, float rB, int p, float AR, float BR,
    int& lo0, int& n0, int& lo1, int& n1)
{
    lo0 = lo1 = 0; n0 = n1 = 0;
    int slo; const int c = cnt_for(A, B, rB, p, slo);
    if (c <= 0) return;
    const int shi = slo + c - 1;
    if (BR == 0.0f) {
        if (AR < 80.0f) { lo0 = slo; n0 = c; } else { lo1 = slo; n1 = c; }
        return;
    }
    float sstar = ((80.0f - AR) * frcp(BR)) * (float)NS - 0.5f;
    sstar = fminf(fmaxf(sstar, -300.0f), 300.0f);
    float lo0f, hi0f, lo1f, hi1f;
    if (BR > 0.0f) {   // fR rising: low-s side is half0
        lo0f = (float)slo;  hi0f = fminf((float)shi, floorf(sstar) + 1.0f);
        lo1f = fmaxf((float)slo, ceilf(sstar) - 1.0f);  hi1f = (float)shi;
    } else {
        lo1f = (float)slo;  hi1f = fminf((float)shi, floorf(sstar) + 1.0f);
        lo0f = fmaxf((float)slo, ceilf(sstar) - 1.0f);  hi0f = (float)shi;
    }
    lo0 = (int)lo0f; n0 = (int)hi0f - lo0 + 1; if (n0 < 0) n0 = 0;
    lo1 = (int)lo1f; n1 = (int)hi1f - lo1 + 1; if (n1 < 0) n1 = 0;
}

__device__ __forceinline__ void plane_range(float A, float B, int& plo, int& phi) {
    const float f0 = A + B * (0.5f / NS);
    const float f1 = A + B * (((float)NS - 0.5f) / NS);
    const float fmn = fminf(f0, f1), fmx = fmaxf(f0, f1);
    plo = (int)fmaxf(ceilf (fmn - 1.01f), 0.0f);
    phi = (int)fminf(floorf(fmx + 1.01f), 159.0f);
}

// ---------------- Stage 1: projection + params + fused count (per ray) ----------------
template<int PA, int PB, int PC, int QS, int QR, int QC>
__device__ __forceinline__ void proj_body(
    const float* __restrict__ img,
    const float* __restrict__ lors,
    float* __restrict__ contrib,
    RayParam* __restrict__ params,
    int* __restrict__ cnt,              // LDS histogram (or nullptr)
    int sa, int sb, int lor)
{
    const int lane = threadIdx.x & 63;

    const float p1x = lors[0*NL + lor];
    const float p1y = lors[1*NL + lor];
    const float p1z = lors[2*NL + lor];
    const float dxv = lors[3*NL + lor] - p1x;
    const float dyv = lors[4*NL + lor] - p1y;
    const float dzv = lors[5*NL + lor] - p1z;
    const float len  = sqrtf(dxv*dxv + dyv*dyv + dzv*dzv);
    const float step = len * (1.0f/NS);

    float2 P00[2], P01[2], P10[2], P11[2];
    float waq[2], wbq[2], wcq[2];

    #pragma unroll
    for (int q = 0; q < 2; ++q) {
        const int s = lane + q*64;
        const float t = ((float)s + 0.5f) * (1.0f/NS);
        const float pos[3] = { p1x + t*dxv, p1y + t*dyv, p1z + t*dzv };
        int ia, ib, ic; float wa, wb, wc;
        coordf(pos[PA], ia, wa);
        coordf(pos[PB], ib, wb);
        coordf(pos[PC], ic, wc);
        const float* g = img + ia*sa + ib*sb + ic;
        __builtin_memcpy(&P00[q], g,            8);
        __builtin_memcpy(&P01[q], g + sb,       8);
        __builtin_memcpy(&P10[q], g + sa,       8);
        __builtin_memcpy(&P11[q], g + sa + sb,  8);
        waq[q] = wa; wbq[q] = wb; wcq[q] = wc;
    }

    float sum = 0.0f;
    #pragma unroll
    for (int q = 0; q < 2; ++q) {
        const float wa = waq[q], wb = wbq[q], wc = wcq[q];
        const float c00 = P00[q].x + wc*(P00[q].y - P00[q].x);
        const float c01 = P01[q].x + wc*(P01[q].y - P01[q].x);
        const float c10 = P10[q].x + wc*(P10[q].y - P10[q].x);
        const float c11 = P11[q].x + wc*(P11[q].y - P11[q].x);
        const float c0  = c00 + wb*(c01 - c00);
        const float c1  = c10 + wb*(c11 - c10);
        sum += c0 + wa*(c1 - c0);
    }

    #pragma unroll
    for (int off = 32; off > 0; off >>= 1)
        sum += __shfl_xor(sum, off, 64);

    // wave-uniform bp geometry (all lanes compute the same bits)
    const float P1v[3] = { p1x, p1y, p1z };
    const float DVv[3] = { dxv, dyv, dzv };
    const float A  = (P1v[QS] + 100.0f)*0.8f - 0.5f;
    const float B  = DVv[QS]*0.8f;
    const float AR = (P1v[QR] + 100.0f)*0.8f - 0.5f;
    const float BR = DVv[QR]*0.8f;
    const float AC = (P1v[QC] + 100.0f)*0.8f - 0.5f;
    const float BC = DVv[QC]*0.8f;

    if (lane == 0) {
        const float cb = 9.0f * step * step * sum;   // KW*(KW*step*sum)*step
        contrib[lor] = cb;
        if (params) {
            float4 a, b;
            a.x = A;  a.y = B;  a.z = AR; a.w = BR;
            b.x = AC; b.y = BC; b.z = cb; b.w = 0.0f;
            params[lor].a = a;
            params[lor].b = b;
        }
    }

    if (cnt) {
        int plo, phi; plane_range(A, B, plo, phi);
        const float rB = frcp(B);
        for (int p = plo + lane; p <= phi; p += 64) {
            int lo0, n0, lo1, n1;
            halves_for(A, B, rB, p, AR, BR, lo0, n0, lo1, n1);
            if (n0 > 0) atomicAdd(&cnt[p*2    ], (n0 + 7) >> 3);
            if (n1 > 0) atomicAdd(&cnt[p*2 + 1], (n1 + 7) >> 3);
        }
    }
}

// 64 rays per WG: each of the 4 waves loops 16 consecutive rays. One
// histogram flush per WG (r17's 4-ray WGs -> 11M hot-line atomics = +400us).
__global__ __launch_bounds__(256) void proj_all(
    const float* __restrict__ img,
    const float* __restrict__ xl, const float* __restrict__ yl,
    const float* __restrict__ zl,
    float* __restrict__ cz, float* __restrict__ cx, float* __restrict__ cy,
    RayParam* __restrict__ params, int* __restrict__ totals)
{
    __shared__ int cnt[NBINS];
    const bool counting = (params != nullptr);
    if (counting) {
        for (int i = threadIdx.x; i < NBINS; i += 256) cnt[i] = 0;
        __syncthreads();
    }
    int* cp = counting ? cnt : nullptr;

    const int wave = threadIdx.x >> 6;
    const int base = blockIdx.x * 64 + wave * 16;

    if (blockIdx.y == 0) {
        for (int it = 0; it < 16; ++it) {
            const int lor = base + it;
            if (lor < NL)
                proj_body<0,1,2, 0,1,2>(img, zl, cz, params ? params : nullptr, cp, GSQ, G, lor);
        }
    } else if (blockIdx.y == 1) {
        for (int it = 0; it < 16; ++it) {
            const int lor = base + it;
            if (lor < NL)
                proj_body<1,2,0, 1,2,0>(img, xl, cx, params ? params + NL : nullptr, cp, GSQ, G, lor);
        }
    } else {
        for (int it = 0; it < 16; ++it) {
            const int lor = base + it;
            if (lor < NL)
                proj_body<0,1,2, 1,0,2>(img, yl, cy, params ? params + 2*NL : nullptr, cp, G, GSQ, lor);
        }
    }

    if (counting) {
        __syncthreads();
        for (int i = threadIdx.x; i < NBINS; i += 256)
            if (cnt[i]) atomicAdd(&totals[i], cnt[i]);
    }
}

// ---------------- K2: tiny scan of 320 totals -> offsets + cursors ----------------
__global__ __launch_bounds__(512) void scan320(
    const int* __restrict__ totals, int* __restrict__ offsets,
    int* __restrict__ cur)
{
    __shared__ int v[NBINS];
    const int tid = threadIdx.x;
    int mine = 0;
    if (tid < NBINS) { mine = totals[tid]; v[tid] = mine; }
    __syncthreads();
    for (int off = 1; off < NBINS; off <<= 1) {
        int x = 0;
        if (tid < NBINS && tid >= off) x = v[tid - off];
        __syncthreads();
        if (tid < NBINS) v[tid] += x;
        __syncthreads();
    }
    if (tid < NBINS) {
        const int excl = v[tid] - mine;
        offsets[tid] = excl;
        cur[tid]     = excl;
    }
    if (tid == 0) offsets[NBINS] = v[NBINS-1];
}

// ---------------- K3: fused reserve + write ----------------
// entry u32: ray[0:17) | s0[17:24) | (n-1)[24:27) | pass[27:29)
__global__ __launch_bounds__(256) void bin_write(
    const RayParam* __restrict__ params, int* __restrict__ cur,
    unsigned* __restrict__ entries)
{
    const int rb = blockIdx.x, pass = blockIdx.y;
    __shared__ int cnt[NBINS];
    __shared__ int base[NBINS];
    for (int i = threadIdx.x; i < NBINS; i += 256) cnt[i] = 0;
    __syncthreads();

    const int r = rb*256 + threadIdx.x;
    float A = 0, B = 0, AR = 0, BR = 0, rB = 0;
    int plo = 0, phi = -1;
    if (r < NL) {
        const float4 a = params[pass*NL + r].a;
        A = a.x; B = a.y; AR = a.z; BR = a.w;
        plane_range(A, B, plo, phi);
        rB = frcp(B);
        for (int p = plo; p <= phi; ++p) {
            int lo0, n0, lo1, n1;
            halves_for(A, B, rB, p, AR, BR, lo0, n0, lo1, n1);
            if (n0 > 0) atomicAdd(&cnt[p*2    ], (n0 + 7) >> 3);
            if (n1 > 0) atomicAdd(&cnt[p*2 + 1], (n1 + 7) >> 3);
        }
    }
    __syncthreads();
    // reserve this WG's chunk per bin via global cursor
    for (int i = threadIdx.x; i < NBINS; i += 256) {
        const int c = cnt[i];
        base[i] = c ? atomicAdd(&cur[i], c) : 0;
    }
    __syncthreads();
    for (int i = threadIdx.x; i < NBINS; i += 256) cnt[i] = 0;  // reuse as local cursor
    __syncthreads();

    if (r < NL) {
        for (int p = plo; p <= phi; ++p) {
            int lo0, n0, lo1, n1;
            halves_for(A, B, rB, p, AR, BR, lo0, n0, lo1, n1);
            #pragma unroll
            for (int h = 0; h < 2; ++h) {
                const int lo = h ? lo1 : lo0;
                const int n  = h ? n1  : n0;
                if (n > 0) {
                    const int bin = p*2 + h;
                    const int ke = (n + 7) >> 3;
                    const int gb = base[bin] + atomicAdd(&cnt[bin], ke);
                    for (int e = 0; e < ke; ++e) {
                        const int s0 = lo + e*8;
                        const int nn = (n - e*8) < 8 ? (n - e*8) : 8;
                        const unsigned enc = (unsigned)r | ((unsigned)s0 << 17)
                                           | ((unsigned)(nn-1) << 24)
                                           | ((unsigned)pass << 27);
                        if (gb + e < ENT_CAP) entries[gb + e] = enc;
                    }
                }
            }
        }
    }
}

// ---------------- bp: strided entries + edge-carry merge, 2 chunks (r16) ----------------
__global__ __launch_bounds__(512) void bp_half(
    const RayParam* __restrict__ params, const int* __restrict__ offsets,
    const unsigned* __restrict__ entries,
    float* __restrict__ out)
{
    __shared__ float tile[81*G];    // 51840 B -> 3 WGs/CU
    const int b   = blockIdx.x;     // bin: p*2 + h
    const int c   = blockIdx.y;     // chunk 0..1
    const int p   = b >> 1;
    const int h   = b & 1;
    const int tid = threadIdx.x;
    const int rowbase = 80 * h;

    for (int j = tid; j < 81*G; j += 512) tile[j] = 0.0f;
    __syncthreads();

    int s0 = offsets[b];
    int e0 = offsets[b+1];
    if (e0 > ENT_CAP) e0 = ENT_CAP;
    if (s0 > e0) s0 = e0;
    const int n  = e0 - s0;
    const int cs = s0 + (n *  c     ) / 2;
    const int ce = s0 + (n * (c + 1)) / 2;

    int e = cs + tid;
    unsigned enc = 0; RayParam rp;
    if (e < ce) {
        enc = entries[e];
        rp  = params[(enc >> 27)*NL + (enc & 0x1FFFF)];
    }

    // pending merged cell: key = rl*G + ic (or -1), accumulators a00..a11
    int   pk  = -1;
    float a00 = 0.0f, a01 = 0.0f, a10 = 0.0f, a11 = 0.0f;

    while (e < ce) {
        const int en = e + 512;
        unsigned encN = 0;
        if (en < ce) encN = entries[en];   // prefetch next entry word

        const int ss = (enc >> 17) & 0x7F;
        const int nn = ((enc >> 24) & 0x7) + 1;
        const float A = rp.a.x, B = rp.a.y, AR = rp.a.z, BR = rp.a.w;
        const float AC = rp.b.x, BC = rp.b.y, cb = rp.b.z;

        for (int i = 0; i < nn; ++i) {
            const float t = ((float)(ss + i) + 0.5f) * (1.0f/NS);
            float fA = A + B*t;
            fA = fminf(fmaxf(fA, 0.0f), 159.0f);
            int ia = (int)fA; ia = ia > 158 ? 158 : ia;
            const float wa = fA - (float)ia;
            float fa;
            if (ia == p)          fa = 1.0f - wa;
            else if (ia == p - 1) fa = wa;
            else                  fa = -1.0f;

            float fR = AR + BR*t;
            fR = fminf(fmaxf(fR, 0.0f), 159.0f);
            int ib = (int)fR; ib = ib > 158 ? 158 : ib;
            const int rl = ib - rowbase;              // exact half test

            if (fa >= 0.0f && rl >= 0 && rl <= 79) {
                float fC = AC + BC*t;
                fC = fminf(fmaxf(fC, 0.0f), 159.0f);
                int ic = (int)fC; ic = ic > 158 ? 158 : ic;
                const float wb = fR - (float)ib;
                const float wc = fC - (float)ic;
                const float v  = fa * cb;
                const float v0 = v * (1.0f - wb), v1 = v * wb;
                const int key = rl*G + ic;
                if (key != pk) {
                    if (pk >= 0) {
                        float* q = tile + pk;
                        const int d = key - pk;
                        if (d == 1) {            // step right: carry right col
                            lds_add(q,     a00);
                            lds_add(q + G, a10);
                            a00 = a01; a10 = a11; a01 = 0.0f; a11 = 0.0f;
                        } else if (d == -1) {    // step left: carry left col
                            lds_add(q + 1,     a01);
                            lds_add(q + G + 1, a11);
                            a01 = a00; a11 = a10; a00 = 0.0f; a10 = 0.0f;
                        } else if (d == G) {     // step down: carry bottom row
                            lds_add(q,     a00);
                            lds_add(q + 1, a01);
                            a00 = a10; a01 = a11; a10 = 0.0f; a11 = 0.0f;
                        } else if (d == -G) {    // step up: carry top row
                            lds_add(q + G,     a10);
                            lds_add(q + G + 1, a11);
                            a10 = a00; a11 = a01; a00 = 0.0f; a01 = 0.0f;
                        } else {                 // generic: flush all
                            lds_add(q,         a00);
                            lds_add(q + 1,     a01);
                            lds_add(q + G,     a10);
                            lds_add(q + G + 1, a11);
                            a00 = 0.0f; a01 = 0.0f; a10 = 0.0f; a11 = 0.0f;
                        }
                    }
                    pk = key;
                }
                a00 += v0 * (1.0f - wc);
                a01 += v0 * wc;
                a10 += v1 * (1.0f - wc);
                a11 += v1 * wc;
            }
        }

        if (en < ce)
            rp = params[(encN >> 27)*NL + (encN & 0x1FFFF)];
        enc = encN; e = en;
    }

    // flush pending cell
    if (pk >= 0) {
        float* q = tile + pk;
        lds_add(q,         a00);
        lds_add(q + 1,     a01);
        lds_add(q + G,     a10);
        lds_add(q + G + 1, a11);
    }
    __syncthreads();

    const int nrows = h ? 80 : 81;
    float* dst = out + (size_t)p * GSQ + (size_t)rowbase * G;
    for (int j = tid; j < nrows*G; j += 512) {
#if __has_builtin(__builtin_amdgcn_global_atomic_fadd_f32)
        unsafeAtomicAdd(&dst[j], tile[j]);
#else
        atomicAdd(&dst[j], tile[j]);
#endif
    }
}

// finalize: out *= img * eff (in place)
__global__ __launch_bounds__(256) void finalize_mul(
    const float4* __restrict__ img, const float4* __restrict__ eff,
    float4* __restrict__ out)
{
    const int i = blockIdx.x * 256 + threadIdx.x;   // over GCUBE/4
    const float4 a = img[i];
    const float4 e = eff[i];
    float4 o = out[i];
    o.x *= a.x * e.x;
    o.y *= a.y * e.y;
    o.z *= a.z * e.z;
    o.w *= a.w * e.w;
    out[i] = o;
}

// ---------------- fallback: fused per-plane scan (round-6, proven) ----------------
template<int PS, int PR, int PC2>
__device__ __forceinline__ void slab_accum(
    float* __restrict__ plane,
    const float* __restrict__ lors,
    const float* __restrict__ contrib,
    int p, int wave, int lane, int nwaves)
{
    for (int base = wave*64; base < NL; base += nwaves*64) {
        const int r = base + lane;
        float A = 0.f, B = 0.f, AR = 0.f, BR = 0.f, AC = 0.f, BC = 0.f, cb = 0.f;
        int slo = 0, cnt = 0;
        if (r < NL) {
            const float q0 = lors[0*NL + r], q1 = lors[1*NL + r], q2 = lors[2*NL + r];
            const float d0 = lors[3*NL + r] - q0;
            const float d1 = lors[4*NL + r] - q1;
            const float d2 = lors[5*NL + r] - q2;
            const float P1[3] = { q0, q1, q2 };
            const float DV[3] = { d0, d1, d2 };
            A  = (P1[PS]  + 100.0f)*0.8f - 0.5f;  B  = DV[PS]*0.8f;
            AR = (P1[PR]  + 100.0f)*0.8f - 0.5f;  BR = DV[PR]*0.8f;
            AC = (P1[PC2] + 100.0f)*0.8f - 0.5f;  BC = DV[PC2]*0.8f;
            cb = contrib[r];
            const float rB = frcp(B);
            cnt = cnt_for(A, B, rB, p, slo);
            if (cnt < 0) cnt = 0;
        }

        int pref = cnt;
        #pragma unroll
        for (int off = 1; off < 64; off <<= 1) {
            const int nsh = __shfl_up(pref, off, 64);
            if (lane >= off) pref += nsh;
        }
        const int total = __shfl(pref, 63, 64);
        const int start = pref - cnt;

        for (int k0 = 0; k0 < total; k0 += 64) {
            const int k  = k0 + lane;
            const int kc = k < total ? k : total - 1;

            int j = 0;
            #pragma unroll
            for (int stp = 32; stp >= 1; stp >>= 1) {
                const int cand = j + stp;
                const int sc = __shfl(start, cand, 64);
                if (cand < 64 && sc <= kc) j = cand;
            }

            const int   sj  = __shfl(slo,   j, 64);
            const int   stj = __shfl(start, j, 64);
            const float Aj  = __shfl(A,  j, 64);
            const float Bj  = __shfl(B,  j, 64);
            const float ARj = __shfl(AR, j, 64);
            const float BRj = __shfl(BR, j, 64);
            const float ACj = __shfl(AC, j, 64);
            const float BCj = __shfl(BC, j, 64);
            const float cbj = __shfl(cb, j, 64);

            const int s = sj + (kc - stj);
            const float t = ((float)s + 0.5f) * (1.0f/NS);
            float fA = Aj + Bj * t;
            fA = fminf(fmaxf(fA, 0.0f), 159.0f);
            int ia = (int)fA; ia = ia > 158 ? 158 : ia;
            const float wa = fA - (float)ia;
            float fa;
            if (ia == p)          fa = 1.0f - wa;
            else if (ia == p - 1) fa = wa;
            else                  fa = -1.0f;

            float fR = ARj + BRj * t;
            float fC = ACj + BCj * t;
            fR = fminf(fmaxf(fR, 0.0f), 159.0f);
            fC = fminf(fmaxf(fC, 0.0f), 159.0f);
            int ib = (int)fR; ib = ib > 158 ? 158 : ib;
            int ic = (int)fC; ic = ic > 158 ? 158 : ic;
            const float wb = fR - (float)ib;
            const float wc = fC - (float)ic;

            if (k < total && fa >= 0.0f) {
                const float v  = fa * cbj;
                const float v0 = v * (1.0f - wb), v1 = v * wb;
                float* q = plane + ib*G + ic;
                lds_add(q,         v0 * (1.0f - wc));
                lds_add(q + 1,     v0 * wc);
                lds_add(q + G,     v1 * (1.0f - wc));
                lds_add(q + G + 1, v1 * wc);
            }
        }
    }
}

__global__ __launch_bounds__(1024) void bp_fused(
    const float* __restrict__ img, const float* __restrict__ eff,
    const float* __restrict__ zl, const float* __restrict__ xl,
    const float* __restrict__ yl,
    const float* __restrict__ cz, const float* __restrict__ cx,
    const float* __restrict__ cy,
    float* __restrict__ out)
{
    __shared__ float plane[GSQ];
    const int p    = blockIdx.x;
    const int tid  = threadIdx.x;
    const int wave = tid >> 6;
    const int lane = tid & 63;

    for (int j = tid; j < GSQ; j += 1024) plane[j] = 0.0f;
    __syncthreads();

    slab_accum<0,1,2>(plane, zl, cz, p, wave, lane, 16);
    slab_accum<1,2,0>(plane, xl, cx, p, wave, lane, 16);
    slab_accum<1,0,2>(plane, yl, cy, p, wave, lane, 16);

    __syncthreads();

    const int pbase = p * GSQ;
    for (int j = tid; j < GSQ; j += 1024) {
        const int idx = pbase + j;
        out[idx] = plane[j] * img[idx] * eff[idx];
    }
}

extern "C" void kernel_launch(void* const* d_in, const int* in_sizes, int n_in,
                              void* d_out, int out_size, void* d_ws, size_t ws_size,
                              hipStream_t stream) {
    const float* img = (const float*)d_in[0];
    const float* eff = (const float*)d_in[1];
    const float* xl  = (const float*)d_in[2];
    const float* yl  = (const float*)d_in[3];
    const float* zl  = (const float*)d_in[4];
    float* out = (float*)d_out;

    const size_t CONTRIB_B = (size_t)3*NL*sizeof(float);       //   600 KB
    const size_t PARAMS_B  = (size_t)3*NL*sizeof(RayParam);    //   4.8 MB
    const size_t TOT_B     = (size_t)NBINS*sizeof(int);        //  1.25 KB
    const size_t OFFS_B    = (size_t)(NBINS+1)*sizeof(int);
    const size_t CUR_B     = (size_t)NBINS*sizeof(int);
    const size_t ENT_B     = (size_t)ENT_CAP*sizeof(unsigned); //    46 MB

    char* w = (char*)d_ws;
    float*    cz      = (float*)w;
    float*    cx      = cz + NL;
    float*    cy      = cx + NL;
    RayParam* params  = (RayParam*)(w + CONTRIB_B);
    int*      totals  = (int*)(w + CONTRIB_B + PARAMS_B);
    int*      offsets = (int*)(w + CONTRIB_B + PARAMS_B + TOT_B);
    int*      cur     = (int*)(w + CONTRIB_B + PARAMS_B + TOT_B + OFFS_B);
    unsigned* entries = (unsigned*)(w + CONTRIB_B + PARAMS_B + TOT_B + OFFS_B + CUR_B);

    const bool binned =
        ws_size >= CONTRIB_B + PARAMS_B + TOT_B + OFFS_B + CUR_B + ENT_B;  // ~51.4 MB

    if (binned) {
        hipMemsetAsync(totals, 0, TOT_B, stream);
        hipMemsetAsync(out, 0, (size_t)GCUBE * sizeof(float), stream);
    }

    proj_all<<<dim3(NRB2, 3), dim3(256), 0, stream>>>(
        img, xl, yl, zl, cz, cx, cy, binned ? params : nullptr,
        binned ? totals : nullptr);

    if (binned) {
        scan320  <<<dim3(1),      dim3(512), 0, stream>>>(totals, offsets, cur);
        bin_write<<<dim3(NRB, 3), dim3(256), 0, stream>>>(params, cur, entries);
        bp_half  <<<dim3(NBINS,2),dim3(512), 0, stream>>>(params, offsets, entries, out);
        finalize_mul<<<dim3(GCUBE/4/256), dim3(256), 0, stream>>>(
            (const float4*)img, (const float4*)eff, (float4*)out);
    } else {
        bp_fused<<<dim3(G), dim3(1024), 0, stream>>>(
            img, eff, zl, xl, yl, cz, cx, cy, out);
    }
}